// Round 6
// baseline (1772.206 us; speedup 1.0000x reference)
//
#include <hip/hip_runtime.h>
#include <hip/hip_fp16.h>

// Workspace: 384 MiB (same layout as rounds 2-5).
//   A [0,128M):   q_h/l -> k_h/l -> qk (f32)
//   D [128,256M): qT_h/l -> P (64M) + vT (64M)
//   E [256,384M): kk_h/l -> value_h
// d_out scratch (dead before final GEMM): wq_h/l, wk_h/l, wv_h

using half8_t = __attribute__((ext_vector_type(8))) _Float16;
using f32x4   = __attribute__((ext_vector_type(4))) float;

static constexpr int NB = 8;
static constexpr int Sd = 2048;
static constexpr long MAT = (long)Sd * Sd;

__device__ __forceinline__ void gload16(const _Float16* g, _Float16* l) {
  __builtin_amdgcn_global_load_lds(
      (const __attribute__((address_space(1))) void*)g,
      (__attribute__((address_space(3))) void*)l, 16, 0, 0);
}
__device__ __forceinline__ void barrier_() { asm volatile("s_barrier" ::: "memory"); }
__device__ __forceinline__ void lgkm0_()   { asm volatile("s_waitcnt lgkmcnt(0)" ::: "memory"); }
#define VMCNT(n) asm volatile("s_waitcnt vmcnt(" #n ")" ::: "memory")
#define SCHEDB() __builtin_amdgcn_sched_barrier(0)

// ---------------------------------------------------------------------------
// presplit: f32 -> fp16 hi (+ residual lo), scaled.
// ---------------------------------------------------------------------------
template<bool SPLIT>
__global__ __launch_bounds__(256) void presplit(const float* __restrict__ in,
    _Float16* __restrict__ h, _Float16* __restrict__ l, long n8, float scl)
{
  long i = (long)blockIdx.x * 256 + threadIdx.x;
  const long stride = (long)gridDim.x * 256;
  for (; i < n8; i += stride) {
    const f32x4* p = (const f32x4*)(in + i * 8);
    f32x4 a = p[0], b = p[1];
    half8_t hh, ll;
#pragma unroll
    for (int j = 0; j < 4; j++) {
      float x = a[j] * scl; _Float16 hv = (_Float16)x;
      hh[j] = hv; if constexpr (SPLIT) ll[j] = (_Float16)(x - (float)hv);
      float y = b[j] * scl; _Float16 hw = (_Float16)y;
      hh[4 + j] = hw; if constexpr (SPLIT) ll[4 + j] = (_Float16)(y - (float)hw);
    }
    *(half8_t*)(h + i * 8) = hh;
    if constexpr (SPLIT) *(half8_t*)(l + i * 8) = ll;
  }
}

// ---------------------------------------------------------------------------
// gemm6 helpers
// ---------------------------------------------------------------------------
__device__ __forceinline__ void lda4(const _Float16* unit, int off, int fmhOff,
                                     half8_t (&a)[4]) {
#pragma unroll
  for (int f = 0; f < 4; f++)
    a[f] = *(const half8_t*)((const char*)unit + off + fmhOff + f * 1024);
}

template<int FMH>
__device__ __forceinline__ void mm16(f32x4 (&acc)[8][4], const half8_t (&a)[4],
                                     const half8_t (&b)[4]) {
  __builtin_amdgcn_s_setprio(1);
#pragma unroll
  for (int f = 0; f < 4; f++)
#pragma unroll
    for (int n = 0; n < 4; n++)
      acc[FMH * 4 + f][n] =
          __builtin_amdgcn_mfma_f32_16x16x32_f16(a[f], b[n], acc[FMH * 4 + f][n], 0, 0, 0);
  __builtin_amdgcn_s_setprio(0);
}

// ---------------------------------------------------------------------------
// gemm6 (B^T form): C[i][j] = cscale * sum_k A[i][k]*B[j][k] (+ bias)
// 256x256 tile, unit = K-half (256x32, 16KB), ring-of-4 per operand.
// m201-discipline, same-phase consumption, ONE barrier per phase:
//   phase A: {8 ds_read_b128 -> BAR -> stage A(u+3) -> lgkm0 -> SCHEDB
//             -> setprio+16 MFMA(fm0-3)}
//   phase B: {4 ds_read_b128 -> VMCNT(6) -> BAR -> stage B(u+3) -> lgkm0
//             -> SCHEDB -> setprio+16 MFMA(fm4-7)}
// VMCNT(6) forces stage(u+1) (6 newer loads outstanding), published by the
// leading-B barrier before any wave reads it; cross-wave LDS/MFMA overlap
// via per-wave lgkm0 after the barrier. 512 threads (8 waves, 2x4).
// NSEG: 1 plain; 3 = K-concat split [Ah|Al|Ah]x[Bh|Bh|Bl] (K=6144).
// BIAS: 0 none, 1 bias[n], 2 bias[m].  OUT: 0 f32, 1 fp16, 2 split fp16(x16).
// ---------------------------------------------------------------------------
template<int NSEG, int BIAS, int OUT>
__global__ __launch_bounds__(512, 2) void gemm6(
    const _Float16* __restrict__ Ah, const _Float16* __restrict__ Al, long sA,
    const _Float16* __restrict__ Bh, const _Float16* __restrict__ Bl, long sB,
    const float* __restrict__ bias, float cscale,
    void* __restrict__ Cp, void* __restrict__ Clp, long sC)
{
  constexpr int H = NSEG * 64;      // K-half units of 32
  __shared__ __align__(16) _Float16 LA[4][8192];   // ring of 4 half-units
  __shared__ __align__(16) _Float16 LB[4][8192];

  const int t = threadIdx.x, w = t >> 6, l = t & 63;

  // XCD swizzle: 512 wgs -> 64 consecutive per XCD (one batch per XCD)
  const int wg = blockIdx.x;
  const int swz = (wg & 7) * 64 + (wg >> 3);
  const int bz = swz >> 6, rem = swz & 63;
  const int by = rem >> 3, bx = rem & 7;

  const _Float16* PAh = Ah + (size_t)bz * sA + (size_t)(by * 256) * Sd;
  const _Float16* PBh = Bh + (size_t)bz * sB + (size_t)(bx * 256) * Sd;
  const _Float16* PAl = (NSEG == 3) ? Al + (size_t)bz * sA + (size_t)(by * 256) * Sd : PAh;
  const _Float16* PBl = (NSEG == 3) ? Bl + (size_t)bz * sB + (size_t)(bx * 256) * Sd : PBh;

  // staging geometry: slot S = i*512 + t -> row 2*(S>>3)+(S&1),
  // k-slot lk = ((S&7)>>1) ^ ((S>>3)&3); dest LDS = linear slot*8.
  const int s7 = t & 7;
  const int lkS = (s7 >> 1) ^ ((t >> 3) & 3);
  const size_t srcoff = (size_t)(2 * (t >> 3) + (s7 & 1)) * Sd + lkS * 8;
  const int du0 = w * 512;

  // read geometry (inverse involution; measured conflict-free)
  const int wm = (w >> 2) * 128, wn = (w & 3) * 64;
  const int lm = l & 15, lkr = l >> 4;
  const int sprime = ((lkr ^ ((lm >> 1) & 3)) << 1) | (lm & 1);
  const int aoff = (wm >> 1) * 128 + (lm >> 1) * 128 + sprime * 16;
  const int boff = (wn >> 1) * 128 + (lm >> 1) * 128 + sprime * 16;

  // half hp -> source pointers / k offset
  auto srcA = [&](int hp) -> const _Float16* {
    if constexpr (NSEG == 3) return ((hp >> 6) == 1) ? PAl : PAh;
    return PAh;
  };
  auto srcB = [&](int hp) -> const _Float16* {
    if constexpr (NSEG == 3) return ((hp >> 6) == 2) ? PBl : PBh;
    return PBh;
  };
  auto koOf = [&](int hp) -> int {
    if constexpr (NSEG == 3) return (hp & 63) * 32;
    return hp * 32;
  };
  auto stageA2 = [&](int hp) {   // 2 global_load_lds (A half-unit)
    const int uu = hp & 3;
    const _Float16* a = srcA(hp) + koOf(hp);
    gload16(a + srcoff, LA[uu] + du0);
    gload16(a + srcoff + (size_t)128 * Sd, LA[uu] + du0 + 4096);
  };
  auto stageB2 = [&](int hp) {   // 2 global_load_lds (B half-unit)
    const int uu = hp & 3;
    const _Float16* b = srcB(hp) + koOf(hp);
    gload16(b + srcoff, LB[uu] + du0);
    gload16(b + srcoff + (size_t)128 * Sd, LB[uu] + du0 + 4096);
  };

  f32x4 acc[8][4] = {};
  half8_t fa[4], fb[4];

  // ---- prologue: stage units 0,1,2 (12 loads); force unit 0; publish
  stageA2(0); stageB2(0); stageA2(1); stageB2(1); stageA2(2); stageB2(2);
  VMCNT(8);
  barrier_();

  for (int u = 0; u < H; ++u) {
    const int slot = u & 3;
    const bool st = (u + 3 < H);
    // ---- phase A: fm0-3 x fn0-3
    lda4(LA[slot], aoff, 0, fa);
    lda4(LB[slot], boff, 0, fb);
    barrier_();
    if (st) stageA2(u + 3);
    lgkm0_(); SCHEDB();
    mm16<0>(acc, fa, fb);
    // ---- phase B: fm4-7 x fn0-3 (fb reused from regs)
    lda4(LA[slot], aoff, 4096, fa);
    if (u + 3 < H)      { VMCNT(6); }   // forces stage(u+1)
    else if (u + 2 < H) { VMCNT(4); }
    else if (u + 1 < H) { VMCNT(0); }
    barrier_();
    if (st) stageB2(u + 3);
    lgkm0_(); SCHEDB();
    mm16<1>(acc, fa, fb);
  }

  // ---- epilogue: C/D layout col = lane&15, row = (lane>>4)*4 + reg
  const int row_base = by * 256 + wm + (lkr << 2);
  const int col_base = bx * 256 + wn + lm;
#pragma unroll
  for (int fm = 0; fm < 8; fm++)
#pragma unroll
    for (int fn = 0; fn < 4; fn++) {
      const int n = col_base + fn * 16;
      float bcol = 0.f;
      if constexpr (BIAS == 1) bcol = bias[n];
#pragma unroll
      for (int r = 0; r < 4; r++) {
        const int m = row_base + fm * 16 + r;
        float v = acc[fm][fn][r] * cscale;
        if constexpr (BIAS == 1) v += bcol;
        if constexpr (BIAS == 2) v += bias[m];
        const size_t ci = (size_t)bz * sC + (size_t)m * Sd + n;
        if constexpr (OUT == 0) ((float*)Cp)[ci] = v;
        else if constexpr (OUT == 1) ((_Float16*)Cp)[ci] = (_Float16)v;
        else {
          float sv = v * 16.0f;
          _Float16 hv = (_Float16)sv;
          ((_Float16*)Cp)[ci]  = hv;
          ((_Float16*)Clp)[ci] = (_Float16)(sv - (float)hv);
        }
      }
    }
}

// ---------------------------------------------------------------------------
// Row softmax: one 256-thread block per row of 2048 f32 -> fp16 probs.
// ---------------------------------------------------------------------------
__global__ __launch_bounds__(256) void softmax_rows(const float* __restrict__ X,
                                                    _Float16* __restrict__ P)
{
  __shared__ float red[4];
  const size_t row = blockIdx.x;
  const float* x = X + row * Sd;
  _Float16* p = P + row * Sd;
  const int t = threadIdx.x;
  float v[8];
  float mx = -1e30f;
#pragma unroll
  for (int i = 0; i < 8; i++) { v[i] = x[t + 256 * i]; mx = fmaxf(mx, v[i]); }
#pragma unroll
  for (int o = 32; o > 0; o >>= 1) mx = fmaxf(mx, __shfl_xor(mx, o, 64));
  if ((t & 63) == 0) red[t >> 6] = mx;
  __syncthreads();
  mx = fmaxf(fmaxf(red[0], red[1]), fmaxf(red[2], red[3]));
  __syncthreads();
  float s = 0.f;
#pragma unroll
  for (int i = 0; i < 8; i++) { v[i] = __expf(v[i] - mx); s += v[i]; }
#pragma unroll
  for (int o = 32; o > 0; o >>= 1) s += __shfl_xor(s, o, 64);
  if ((t & 63) == 0) red[t >> 6] = s;
  __syncthreads();
  s = red[0] + red[1] + red[2] + red[3];
  float inv = 1.f / s;
#pragma unroll
  for (int i = 0; i < 8; i++) p[t + 256 * i] = (_Float16)(v[i] * inv);
}

// ---------------------------------------------------------------------------
extern "C" void kernel_launch(void* const* d_in, const int* in_sizes, int n_in,
                              void* d_out, int out_size, void* d_ws, size_t ws_size,
                              hipStream_t stream)
{
  const float* query = (const float*)d_in[0];
  const float* key_  = (const float*)d_in[1];
  const float* value = (const float*)d_in[2];
  const float* Wq = (const float*)d_in[3];
  const float* bq = (const float*)d_in[4];
  const float* Wk = (const float*)d_in[5];
  const float* bk = (const float*)d_in[6];
  const float* Wv = (const float*)d_in[7];
  const float* bv = (const float*)d_in[8];

  char* ws = (char*)d_ws;
  char* ob = (char*)d_out;
  const size_t M64 = (size_t)NB * MAT * 2;   // 64 MiB

  _Float16* q_h  = (_Float16*)(ws);
  _Float16* q_l  = (_Float16*)(ws + M64);
  _Float16* k_h  = q_h;
  _Float16* k_l  = q_l;
  float*    qk   = (float*)(ws);
  _Float16* qT_h = (_Float16*)(ws + 2 * M64);
  _Float16* qT_l = (_Float16*)(ws + 3 * M64);
  _Float16* P    = qT_h;
  _Float16* vT   = qT_l;
  _Float16* kk_h = (_Float16*)(ws + 4 * M64);
  _Float16* kk_l = (_Float16*)(ws + 5 * M64);
  _Float16* val_h = kk_h;

  _Float16* wq_h = (_Float16*)(ob);
  _Float16* wq_l = (_Float16*)(ob + (MAT * 2));
  _Float16* wk_h = (_Float16*)(ob + 2 * (MAT * 2));
  _Float16* wk_l = (_Float16*)(ob + 3 * (MAT * 2));
  _Float16* wv_h = (_Float16*)(ob + 4 * (MAT * 2));
  float* out = (float*)d_out;

  dim3 blk256(256), blk512(512);
  dim3 gg(512);   // 8 batches x 8x8 tiles of 256
  const long NQ8 = (long)NB * MAT / 8;
  const long NW8 = MAT / 8;

  // 1. presplit query (x16), Wq (x16)
  presplit<true><<<dim3(2048), blk256, 0, stream>>>(query, q_h, q_l, NQ8, 16.f);
  presplit<true><<<dim3(2048), blk256, 0, stream>>>(Wq, wq_h, wq_l, NW8, 16.f);
  // 2. qT[e][s] = sum_d Wq[e][d]*query[s][d] + bq[e] (row bias), split out
  gemm6<3, 2, 2><<<gg, blk512, 0, stream>>>(wq_h, wq_l, 0, q_h, q_l, MAT,
                                            bq, 1.f / 256.f, qT_h, qT_l, MAT);
  // 3. presplit key_ (x16), Wk (x16)
  presplit<true><<<dim3(2048), blk256, 0, stream>>>(key_, k_h, k_l, NQ8, 16.f);
  presplit<true><<<dim3(2048), blk256, 0, stream>>>(Wk, wk_h, wk_l, NW8, 16.f);
  // 4. kk[s'][e] = sum_d key_[s'][d]*Wk[e][d] + bk[e] (col bias), split out
  gemm6<3, 1, 2><<<gg, blk512, 0, stream>>>(k_h, k_l, MAT, wk_h, wk_l, 0,
                                            bk, 1.f / 256.f, kk_h, kk_l, MAT);
  // 5. qk[e][s'] = sum_m qT[e][m]*kk[s'][m]  (f32 out)
  gemm6<3, 0, 0><<<gg, blk512, 0, stream>>>(qT_h, qT_l, MAT, kk_h, kk_l, MAT,
                                            nullptr, 1.f / 256.f, qk, nullptr, MAT);
  // 6. P = row-softmax(qk), fp16
  softmax_rows<<<dim3(NB * Sd), blk256, 0, stream>>>(qk, P);
  // 7. presplit value (x1), Wv (x1)
  presplit<false><<<dim3(2048), blk256, 0, stream>>>(value, val_h, nullptr, NQ8, 1.f);
  presplit<false><<<dim3(2048), blk256, 0, stream>>>(Wv, wv_h, nullptr, NW8, 1.f);
  // 8. vT[d'][s'] = sum_d Wv[d'][d]*value[s'][d] + bv[d'] (row bias), fp16
  gemm6<1, 2, 1><<<gg, blk512, 0, stream>>>(wv_h, nullptr, 0, val_h, nullptr, MAT,
                                            bv, 1.f, vT, nullptr, MAT);
  // 9. out[d'][e] = sum_s' vT[d'][s']*P[e][s']  (f32 -> d_out)
  gemm6<1, 0, 0><<<gg, blk512, 0, stream>>>(vT, nullptr, MAT, P, nullptr, MAT,
                                            nullptr, 1.f, out, nullptr, MAT);
}

// Round 7
// 1292.747 us; speedup vs baseline: 1.3709x; 1.3709x over previous
//
#include <hip/hip_runtime.h>
#include <hip/hip_fp16.h>

// Workspace: 384 MiB.
//   A [0,128M):   q_h (64M) -> k_h/k_l -> qk (f32, 128M)
//   D [128,256M): qT_h/qT_l -> P (64M) + vT (64M)
//   E [256,384M): kk_h (64M) + val_h (64M)
// d_out scratch (dead before final GEMM): wq_h/l, wk_h, wv_h (16M)

using half8_t = __attribute__((ext_vector_type(8))) _Float16;
using f32x4   = __attribute__((ext_vector_type(4))) float;

static constexpr int NB = 8;
static constexpr int Sd = 2048;
static constexpr long MAT = (long)Sd * Sd;

__device__ __forceinline__ void gload16(const _Float16* g, _Float16* l) {
  __builtin_amdgcn_global_load_lds(
      (const __attribute__((address_space(1))) void*)g,
      (__attribute__((address_space(3))) void*)l, 16, 0, 0);
}
__device__ __forceinline__ void barrier_() { asm volatile("s_barrier" ::: "memory"); }
__device__ __forceinline__ void lgkm0_()   { asm volatile("s_waitcnt lgkmcnt(0)" ::: "memory"); }
#define VMCNT(n) asm volatile("s_waitcnt vmcnt(" #n ")" ::: "memory")
#define SCHEDB() __builtin_amdgcn_sched_barrier(0)

// ---------------------------------------------------------------------------
// presplit: f32 -> fp16 hi (+ residual lo if SPLIT), scaled.
// ---------------------------------------------------------------------------
template<bool SPLIT>
__global__ __launch_bounds__(256) void presplit(const float* __restrict__ in,
    _Float16* __restrict__ h, _Float16* __restrict__ l, long n8, float scl)
{
  long i = (long)blockIdx.x * 256 + threadIdx.x;
  const long stride = (long)gridDim.x * 256;
  for (; i < n8; i += stride) {
    const f32x4* p = (const f32x4*)(in + i * 8);
    f32x4 a = p[0], b = p[1];
    half8_t hh, ll;
#pragma unroll
    for (int j = 0; j < 4; j++) {
      float x = a[j] * scl; _Float16 hv = (_Float16)x;
      hh[j] = hv; if constexpr (SPLIT) ll[j] = (_Float16)(x - (float)hv);
      float y = b[j] * scl; _Float16 hw = (_Float16)y;
      hh[4 + j] = hw; if constexpr (SPLIT) ll[4 + j] = (_Float16)(y - (float)hw);
    }
    *(half8_t*)(h + i * 8) = hh;
    if constexpr (SPLIT) *(half8_t*)(l + i * 8) = ll;
  }
}

// ---------------------------------------------------------------------------
// gemm7 helpers
// ---------------------------------------------------------------------------
__device__ __forceinline__ void lda4(const _Float16* unit, int off, int fmhOff,
                                     half8_t (&a)[4]) {
#pragma unroll
  for (int f = 0; f < 4; f++)
    a[f] = *(const half8_t*)((const char*)unit + off + fmhOff + f * 1024);
}

template<int FMH>
__device__ __forceinline__ void mm16(f32x4 (&acc)[8][4], const half8_t (&a)[4],
                                     const half8_t (&b)[4]) {
  __builtin_amdgcn_s_setprio(1);
#pragma unroll
  for (int f = 0; f < 4; f++)
#pragma unroll
    for (int n = 0; n < 4; n++)
      acc[FMH * 4 + f][n] =
          __builtin_amdgcn_mfma_f32_16x16x32_f16(a[f], b[n], acc[FMH * 4 + f][n], 0, 0, 0);
  __builtin_amdgcn_s_setprio(0);
}

// ---------------------------------------------------------------------------
// gemm7 (B^T form): C[i][j] = cscale * sum_k A[i][k]*B[j][k] (+ bias)
// 256x256 tile, unit = K-half (256x32, 16KB), ring-of-4 per operand.
// m201 discipline (faithful): per phase
//   {ds_reads -> stage (pre-barrier) -> [vmcnt chain, phase B only] ->
//    barrier -> lgkm0 -> sched_barrier -> setprio+16 MFMA -> barrier}
// Cross-wave LDS/MFMA overlap: s_barrier does not drain lgkm; each wave
// waits only its own reads, early-served waves MFMA while LDS drains rest.
// VMCNT(8) end-of-unit forces stage(u+1) (12 outstanding - 4), published
// by the following barrier. 512 threads (8 waves, 2x4).
// NSEG: 1 plain; 2 = K-concat split [Ah|Al]x[Bh|Bh] (K=4096).
// BIAS: 0 none, 1 bias[n], 2 bias[m].
// OUT: 0 f32, 1 fp16, 2 split fp16 (x16), 3 fp16 hi-only (x16).
// ---------------------------------------------------------------------------
template<int NSEG, int BIAS, int OUT>
__global__ __launch_bounds__(512, 2) void gemm7(
    const _Float16* __restrict__ Ah, const _Float16* __restrict__ Al, long sA,
    const _Float16* __restrict__ Bh, long sB,
    const float* __restrict__ bias, float cscale,
    void* __restrict__ Cp, void* __restrict__ Clp, long sC)
{
  constexpr int H = NSEG * 64;      // K-half units of 32
  __shared__ __align__(16) _Float16 LA[4][8192];   // ring of 4 half-units
  __shared__ __align__(16) _Float16 LB[4][8192];

  const int t = threadIdx.x, w = t >> 6, l = t & 63;

  // XCD swizzle: 512 wgs -> 64 consecutive per XCD (one batch per XCD)
  const int wg = blockIdx.x;
  const int swz = (wg & 7) * 64 + (wg >> 3);
  const int bz = swz >> 6, rem = swz & 63;
  const int by = rem >> 3, bx = rem & 7;

  const _Float16* PAh = Ah + (size_t)bz * sA + (size_t)(by * 256) * Sd;
  const _Float16* PBh = Bh + (size_t)bz * sB + (size_t)(bx * 256) * Sd;
  const _Float16* PAl = (NSEG == 2)
      ? Al + (size_t)bz * sA + (size_t)(by * 256) * Sd : PAh;

  // staging geometry: slot S = i*512 + t -> row 2*(S>>3)+(S&1),
  // k-slot lk = ((S&7)>>1) ^ ((S>>3)&3); dest LDS = linear slot*8.
  const int s7 = t & 7;
  const int lkS = (s7 >> 1) ^ ((t >> 3) & 3);
  const size_t srcoff = (size_t)(2 * (t >> 3) + (s7 & 1)) * Sd + lkS * 8;
  const int du0 = w * 512;

  // read geometry (inverse involution; measured conflict-free)
  const int wm = (w >> 2) * 128, wn = (w & 3) * 64;
  const int lm = l & 15, lkr = l >> 4;
  const int sprime = ((lkr ^ ((lm >> 1) & 3)) << 1) | (lm & 1);
  const int aoff = (wm >> 1) * 128 + (lm >> 1) * 128 + sprime * 16;
  const int boff = (wn >> 1) * 128 + (lm >> 1) * 128 + sprime * 16;

  // half hp -> source pointers / k offset
  auto srcA = [&](int hp) -> const _Float16* {
    if constexpr (NSEG == 2) return (hp >> 6) ? PAl : PAh;
    return PAh;
  };
  auto koOf = [&](int hp) -> int {
    if constexpr (NSEG == 2) return (hp & 63) * 32;
    return hp * 32;
  };
  auto stageA2 = [&](int hp) {   // 2 global_load_lds (A half-unit)
    const int uu = hp & 3;
    const _Float16* a = srcA(hp) + koOf(hp);
    gload16(a + srcoff, LA[uu] + du0);
    gload16(a + srcoff + (size_t)128 * Sd, LA[uu] + du0 + 4096);
  };
  auto stageB2 = [&](int hp) {   // 2 global_load_lds (B half-unit)
    const int uu = hp & 3;
    const _Float16* b = PBh + koOf(hp);
    gload16(b + srcoff, LB[uu] + du0);
    gload16(b + srcoff + (size_t)128 * Sd, LB[uu] + du0 + 4096);
  };

  f32x4 acc[8][4] = {};
  half8_t fa[4], fb[4];

  // ---- prologue: stage units 0,1,2 (12 loads); force unit 0; publish
  stageA2(0); stageB2(0); stageA2(1); stageB2(1); stageA2(2); stageB2(2);
  VMCNT(8);
  barrier_();

  for (int u = 0; u < H; ++u) {
    const int slot = u & 3;
    const bool st = (u + 3 < H);
    // ---- phase A: fm0-3 x fn0-3
    lda4(LA[slot], aoff, 0, fa);
    lda4(LB[slot], boff, 0, fb);
    if (st) stageA2(u + 3);
    barrier_();
    lgkm0_(); SCHEDB();
    mm16<0>(acc, fa, fb);
    barrier_();
    // ---- phase B: fm4-7 x fn0-3 (fb reused from regs)
    lda4(LA[slot], aoff, 4096, fa);
    if (st) stageB2(u + 3);
    if (u + 3 < H)      { VMCNT(8); }   // forces stage(u+1)
    else if (u + 2 < H) { VMCNT(4); }
    else if (u + 1 < H) { VMCNT(0); }
    barrier_();
    lgkm0_(); SCHEDB();
    mm16<1>(acc, fa, fb);
    barrier_();
  }

  // ---- epilogue: C/D layout col = lane&15, row = (lane>>4)*4 + reg
  const int row_base = by * 256 + wm + (lkr << 2);
  const int col_base = bx * 256 + wn + lm;
#pragma unroll
  for (int fm = 0; fm < 8; fm++)
#pragma unroll
    for (int fn = 0; fn < 4; fn++) {
      const int n = col_base + fn * 16;
      float bcol = 0.f;
      if constexpr (BIAS == 1) bcol = bias[n];
#pragma unroll
      for (int r = 0; r < 4; r++) {
        const int m = row_base + fm * 16 + r;
        float v = acc[fm][fn][r] * cscale;
        if constexpr (BIAS == 1) v += bcol;
        if constexpr (BIAS == 2) v += bias[m];
        const size_t ci = (size_t)bz * sC + (size_t)m * Sd + n;
        if constexpr (OUT == 0) ((float*)Cp)[ci] = v;
        else if constexpr (OUT == 1) ((_Float16*)Cp)[ci] = (_Float16)v;
        else if constexpr (OUT == 3) ((_Float16*)Cp)[ci] = (_Float16)(v * 16.0f);
        else {
          float sv = v * 16.0f;
          _Float16 hv = (_Float16)sv;
          ((_Float16*)Cp)[ci]  = hv;
          ((_Float16*)Clp)[ci] = (_Float16)(sv - (float)hv);
        }
      }
    }
}

// ---------------------------------------------------------------------------
// Row softmax: one 256-thread block per row of 2048 f32 -> fp16 probs.
// ---------------------------------------------------------------------------
__global__ __launch_bounds__(256) void softmax_rows(const float* __restrict__ X,
                                                    _Float16* __restrict__ P)
{
  __shared__ float red[4];
  const size_t row = blockIdx.x;
  const float* x = X + row * Sd;
  _Float16* p = P + row * Sd;
  const int t = threadIdx.x;
  float v[8];
  float mx = -1e30f;
#pragma unroll
  for (int i = 0; i < 8; i++) { v[i] = x[t + 256 * i]; mx = fmaxf(mx, v[i]); }
#pragma unroll
  for (int o = 32; o > 0; o >>= 1) mx = fmaxf(mx, __shfl_xor(mx, o, 64));
  if ((t & 63) == 0) red[t >> 6] = mx;
  __syncthreads();
  mx = fmaxf(fmaxf(red[0], red[1]), fmaxf(red[2], red[3]));
  __syncthreads();
  float s = 0.f;
#pragma unroll
  for (int i = 0; i < 8; i++) { v[i] = __expf(v[i] - mx); s += v[i]; }
#pragma unroll
  for (int o = 32; o > 0; o >>= 1) s += __shfl_xor(s, o, 64);
  if ((t & 63) == 0) red[t >> 6] = s;
  __syncthreads();
  s = red[0] + red[1] + red[2] + red[3];
  float inv = 1.f / s;
#pragma unroll
  for (int i = 0; i < 8; i++) p[t + 256 * i] = (_Float16)(v[i] * inv);
}

// ---------------------------------------------------------------------------
extern "C" void kernel_launch(void* const* d_in, const int* in_sizes, int n_in,
                              void* d_out, int out_size, void* d_ws, size_t ws_size,
                              hipStream_t stream)
{
  const float* query = (const float*)d_in[0];
  const float* key_  = (const float*)d_in[1];
  const float* value = (const float*)d_in[2];
  const float* Wq = (const float*)d_in[3];
  const float* bq = (const float*)d_in[4];
  const float* Wk = (const float*)d_in[5];
  const float* bk = (const float*)d_in[6];
  const float* Wv = (const float*)d_in[7];
  const float* bv = (const float*)d_in[8];

  char* ws = (char*)d_ws;
  char* ob = (char*)d_out;
  const size_t M64 = (size_t)NB * MAT * 2;   // 64 MiB

  _Float16* q_h  = (_Float16*)(ws);                 // A[0,64)
  _Float16* k_h  = (_Float16*)(ws);                 // A[0,64) (q dead)
  _Float16* k_l  = (_Float16*)(ws + M64);           // A[64,128)
  float*    qk   = (float*)(ws);                    // A as f32 (k dead)
  _Float16* qT_h = (_Float16*)(ws + 2 * M64);       // D[128,192)
  _Float16* qT_l = (_Float16*)(ws + 3 * M64);       // D[192,256)
  _Float16* P    = qT_h;                            // after qT dead
  _Float16* vT   = qT_l;
  _Float16* kk_h = (_Float16*)(ws + 4 * M64);       // E[256,320)
  _Float16* val_h = (_Float16*)(ws + 5 * M64);      // E[320,384)

  _Float16* wq_h = (_Float16*)(ob);
  _Float16* wq_l = (_Float16*)(ob + (MAT * 2));
  _Float16* wk_h = (_Float16*)(ob + 2 * (MAT * 2));
  _Float16* wv_h = (_Float16*)(ob + 3 * (MAT * 2));
  float* out = (float*)d_out;

  dim3 blk256(256), blk512(512);
  dim3 gg(512);   // 8 batches x 8x8 tiles of 256
  const long NQ8 = (long)NB * MAT / 8;
  const long NW8 = MAT / 8;

  // 1. presplit query (hi only, x16), Wq (hi+lo, x16)
  presplit<false><<<dim3(2048), blk256, 0, stream>>>(query, q_h, nullptr, NQ8, 16.f);
  presplit<true><<<dim3(2048), blk256, 0, stream>>>(Wq, wq_h, wq_l, NW8, 16.f);
  // 2. qT[e][s] = sum_d Wq[e][d]*query[s][d] + bq[e] (row bias), split out
  //    kept: (Wqh+Wql)*query_h
  gemm7<2, 2, 2><<<gg, blk512, 0, stream>>>(wq_h, wq_l, 0, q_h, MAT,
                                            bq, 1.f / 256.f, qT_h, qT_l, MAT);
  // 3. presplit key_ (hi+lo, x16), Wk (hi only, x16)
  presplit<true><<<dim3(2048), blk256, 0, stream>>>(key_, k_h, k_l, NQ8, 16.f);
  presplit<false><<<dim3(2048), blk256, 0, stream>>>(Wk, wk_h, nullptr, NW8, 16.f);
  // 4. kk[s'][e] = sum_d key_[s'][d]*Wk[e][d] + bk[e] (col bias), hi-only out
  //    kept: (kh+kl)*Wkh
  gemm7<2, 1, 3><<<gg, blk512, 0, stream>>>(k_h, k_l, MAT, wk_h, 0,
                                            bk, 1.f / 256.f, kk_h, nullptr, MAT);
  // 5. qk[e][s'] = sum_m qT[e][m]*kk[s'][m]  (f32 out); kept: (qh+ql)*kk_h
  gemm7<2, 0, 0><<<gg, blk512, 0, stream>>>(qT_h, qT_l, MAT, kk_h, MAT,
                                            nullptr, 1.f / 256.f, qk, nullptr, MAT);
  // 6. P = row-softmax(qk), fp16
  softmax_rows<<<dim3(NB * Sd), blk256, 0, stream>>>(qk, P);
  // 7. presplit value (x1), Wv (x1)
  presplit<false><<<dim3(2048), blk256, 0, stream>>>(value, val_h, nullptr, NQ8, 1.f);
  presplit<false><<<dim3(2048), blk256, 0, stream>>>(Wv, wv_h, nullptr, NW8, 1.f);
  // 8. vT[d'][s'] = sum_d Wv[d'][d]*value[s'][d] + bv[d'] (row bias), fp16
  gemm7<1, 2, 1><<<gg, blk512, 0, stream>>>(wv_h, nullptr, 0, val_h, MAT,
                                            bv, 1.f, vT, nullptr, MAT);
  // 9. out[d'][e] = sum_s' vT[d'][s']*P[e][s']  (f32 -> d_out)
  gemm7<1, 0, 0><<<gg, blk512, 0, stream>>>(vT, nullptr, MAT, P, MAT,
                                            nullptr, 1.f, out, nullptr, MAT);
}

// Round 8
// 1265.064 us; speedup vs baseline: 1.4009x; 1.0219x over previous
//
#include <hip/hip_runtime.h>
#include <hip/hip_fp16.h>

// Workspace: 384 MiB.
//   A [0,128M):   q_h (64M) -> k_h/k_l -> qk (f32, 128M)
//   D [128,256M): qT_h/qT_l -> P (64M) + vT (64M)
//   E [256,384M): kk_h (64M) + val_h (64M)
// d_out scratch (dead before final GEMM): wq_h/l, wk_h, wv_h

using half8_t = __attribute__((ext_vector_type(8))) _Float16;
using f32x4   = __attribute__((ext_vector_type(4))) float;

static constexpr int NB = 8;
static constexpr int Sd = 2048;
static constexpr long MAT = (long)Sd * Sd;

__device__ __forceinline__ void gload16(const _Float16* g, _Float16* l) {
  __builtin_amdgcn_global_load_lds(
      (const __attribute__((address_space(1))) void*)g,
      (__attribute__((address_space(3))) void*)l, 16, 0, 0);
}
// NOTE: no "memory" clobber — keeps the compiler's lgkm scoreboard precise
// so ds_read->MFMA waits stay COUNTED across the loop back-edge.
#define VMCNT(n) asm volatile("s_waitcnt vmcnt(" #n ")")
#define BAR()    __builtin_amdgcn_s_barrier()
#define SCHEDB() __builtin_amdgcn_sched_barrier(0)

// ---------------------------------------------------------------------------
// presplit: f32 -> fp16 hi (+ residual lo if SPLIT), scaled.
// ---------------------------------------------------------------------------
template<bool SPLIT>
__global__ __launch_bounds__(256) void presplit(const float* __restrict__ in,
    _Float16* __restrict__ h, _Float16* __restrict__ l, long n8, float scl)
{
  long i = (long)blockIdx.x * 256 + threadIdx.x;
  const long stride = (long)gridDim.x * 256;
  for (; i < n8; i += stride) {
    const f32x4* p = (const f32x4*)(in + i * 8);
    f32x4 a = p[0], b = p[1];
    half8_t hh, ll;
#pragma unroll
    for (int j = 0; j < 4; j++) {
      float x = a[j] * scl; _Float16 hv = (_Float16)x;
      hh[j] = hv; if constexpr (SPLIT) ll[j] = (_Float16)(x - (float)hv);
      float y = b[j] * scl; _Float16 hw = (_Float16)y;
      hh[4 + j] = hw; if constexpr (SPLIT) ll[4 + j] = (_Float16)(y - (float)hw);
    }
    *(half8_t*)(h + i * 8) = hh;
    if constexpr (SPLIT) *(half8_t*)(l + i * 8) = ll;
  }
}

// ---------------------------------------------------------------------------
// gemm8 (B^T form): C[i][j] = cscale * sum_k A[i][k]*B[j][k] (+ bias)
// 256x256 tile, unit = K-half (256x32, 16KB), ring-of-4 per operand.
// Per unit u: {12 ds_read (unit u+1 frags, alt reg set) -> SCHEDB ->
//   32 MFMA on unit u's frags (compiler-counted lgkm wait) -> SCHEDB ->
//   stage unit u+3 (4 global_load_lds) -> vmcnt(4) [forces stage u+2] ->
//   s_barrier [publishes u+2]}. One barrier + one counted vmcnt per unit;
// no memory-clobbering asm anywhere on the ds_read->MFMA path.
// WAR: stage(u+3) overwrites slot(u-1), drained by mfma(u-1)'s wait one
// iteration earlier. 512 threads (8 waves, 2x4).
// NSEG: 1 plain; 2 = K-concat split [Ah|Al]x[Bh|Bh] (K=4096).
// BIAS: 0 none, 1 bias[n], 2 bias[m].
// OUT: 0 f32, 1 fp16, 2 split fp16 (x16), 3 fp16 hi-only (x16).
// ---------------------------------------------------------------------------
template<int NSEG, int BIAS, int OUT>
__global__ __launch_bounds__(512, 2) void gemm8(
    const _Float16* __restrict__ Ah, const _Float16* __restrict__ Al, long sA,
    const _Float16* __restrict__ Bh, long sB,
    const float* __restrict__ bias, float cscale,
    void* __restrict__ Cp, void* __restrict__ Clp, long sC)
{
  constexpr int H = NSEG * 64;      // K-half units of 32
  __shared__ __align__(16) _Float16 LA[4][8192];   // ring of 4 half-units
  __shared__ __align__(16) _Float16 LB[4][8192];

  const int t = threadIdx.x, w = t >> 6, l = t & 63;

  // XCD swizzle: 512 wgs -> 64 consecutive per XCD (one batch per XCD)
  const int wg = blockIdx.x;
  const int swz = (wg & 7) * 64 + (wg >> 3);
  const int bz = swz >> 6, rem = swz & 63;
  const int by = rem >> 3, bx = rem & 7;

  const _Float16* PAh = Ah + (size_t)bz * sA + (size_t)(by * 256) * Sd;
  const _Float16* PBh = Bh + (size_t)bz * sB + (size_t)(bx * 256) * Sd;
  const _Float16* PAl = (NSEG == 2)
      ? Al + (size_t)bz * sA + (size_t)(by * 256) * Sd : PAh;

  // staging geometry: slot S = i*512 + t -> row 2*(S>>3)+(S&1),
  // k-slot lk = ((S&7)>>1) ^ ((S>>3)&3); dest LDS = linear slot*8.
  const int s7 = t & 7;
  const int lkS = (s7 >> 1) ^ ((t >> 3) & 3);
  const size_t srcoff = (size_t)(2 * (t >> 3) + (s7 & 1)) * Sd + lkS * 8;
  const int du0 = w * 512;

  // read geometry (inverse involution; measured conflict-free)
  const int wm = (w >> 2) * 128, wn = (w & 3) * 64;
  const int lm = l & 15, lkr = l >> 4;
  const int sprime = ((lkr ^ ((lm >> 1) & 3)) << 1) | (lm & 1);
  const int aoff = (wm >> 1) * 128 + (lm >> 1) * 128 + sprime * 16;
  const int boff = (wn >> 1) * 128 + (lm >> 1) * 128 + sprime * 16;

  // half hp -> source pointer / k offset
  auto srcA = [&](int hp) -> const _Float16* {
    if constexpr (NSEG == 2) return (hp >> 6) ? PAl : PAh;
    return PAh;
  };
  auto koOf = [&](int hp) -> int {
    if constexpr (NSEG == 2) return (hp & 63) * 32;
    return hp * 32;
  };
  auto stageU = [&](int hp) {   // 4 global_load_lds (A + B half-units)
    const int uu = hp & 3;
    const _Float16* a = srcA(hp) + koOf(hp);
    const _Float16* b = PBh + koOf(hp);
    gload16(a + srcoff, LA[uu] + du0);
    gload16(a + srcoff + (size_t)128 * Sd, LA[uu] + du0 + 4096);
    gload16(b + srcoff, LB[uu] + du0);
    gload16(b + srcoff + (size_t)128 * Sd, LB[uu] + du0 + 4096);
  };

  f32x4 acc[8][4] = {};
  half8_t a0[8], b0[4], a1[8], b1[4];

  auto readF = [&](int slot, half8_t (&fa)[8], half8_t (&fb)[4]) {  // 12 b128
#pragma unroll
    for (int f = 0; f < 8; f++)
      fa[f] = *(const half8_t*)((const char*)LA[slot] + aoff + f * 1024);
#pragma unroll
    for (int n = 0; n < 4; n++)
      fb[n] = *(const half8_t*)((const char*)LB[slot] + boff + n * 1024);
  };
  auto mfma32 = [&](const half8_t (&fa)[8], const half8_t (&fb)[4]) {
    __builtin_amdgcn_s_setprio(1);
#pragma unroll
    for (int f = 0; f < 8; f++)
#pragma unroll
      for (int n = 0; n < 4; n++)
        acc[f][n] = __builtin_amdgcn_mfma_f32_16x16x32_f16(fa[f], fb[n], acc[f][n], 0, 0, 0);
    __builtin_amdgcn_s_setprio(0);
  };

  // ---- prologue: stage units 0,1,2 (12 loads); force 0,1; publish; read 0
  stageU(0); stageU(1); stageU(2);
  VMCNT(4);
  BAR();
  readF(0, a0, b0);

  // ---- main loop, unrolled x2 for static frag-set indexing (H is even)
  for (int j = 0; j < H / 2; ++j) {
    {   // even unit u = 2j, consumes (a0,b0), reads into (a1,b1)
      const int u = 2 * j;
      readF((u + 1) & 3, a1, b1);
      SCHEDB();
      mfma32(a0, b0);
      SCHEDB();
      if (u + 3 < H) { stageU(u + 3); VMCNT(4); }
      BAR();
    }
    {   // odd unit u = 2j+1, consumes (a1,b1), reads into (a0,b0)
      const int u = 2 * j + 1;
      if (u + 1 < H) readF((u + 1) & 3, a0, b0);
      SCHEDB();
      mfma32(a1, b1);
      SCHEDB();
      if (u + 3 < H)      { stageU(u + 3); VMCNT(4); }
      else if (u == H - 3) { VMCNT(0); }   // force last stage (H-1)
      if (u + 1 < H) BAR();
    }
  }

  // ---- epilogue: C/D layout col = lane&15, row = (lane>>4)*4 + reg
  const int row_base = by * 256 + wm + (lkr << 2);
  const int col_base = bx * 256 + wn + lm;
#pragma unroll
  for (int fm = 0; fm < 8; fm++)
#pragma unroll
    for (int fn = 0; fn < 4; fn++) {
      const int n = col_base + fn * 16;
      float bcol = 0.f;
      if constexpr (BIAS == 1) bcol = bias[n];
#pragma unroll
      for (int r = 0; r < 4; r++) {
        const int m = row_base + fm * 16 + r;
        float v = acc[fm][fn][r] * cscale;
        if constexpr (BIAS == 1) v += bcol;
        if constexpr (BIAS == 2) v += bias[m];
        const size_t ci = (size_t)bz * sC + (size_t)m * Sd + n;
        if constexpr (OUT == 0) ((float*)Cp)[ci] = v;
        else if constexpr (OUT == 1) ((_Float16*)Cp)[ci] = (_Float16)v;
        else if constexpr (OUT == 3) ((_Float16*)Cp)[ci] = (_Float16)(v * 16.0f);
        else {
          float sv = v * 16.0f;
          _Float16 hv = (_Float16)sv;
          ((_Float16*)Cp)[ci]  = hv;
          ((_Float16*)Clp)[ci] = (_Float16)(sv - (float)hv);
        }
      }
    }
}

// ---------------------------------------------------------------------------
// Row softmax: one 256-thread block per row of 2048 f32 -> fp16 probs.
// ---------------------------------------------------------------------------
__global__ __launch_bounds__(256) void softmax_rows(const float* __restrict__ X,
                                                    _Float16* __restrict__ P)
{
  __shared__ float red[4];
  const size_t row = blockIdx.x;
  const float* x = X + row * Sd;
  _Float16* p = P + row * Sd;
  const int t = threadIdx.x;
  float v[8];
  float mx = -1e30f;
#pragma unroll
  for (int i = 0; i < 8; i++) { v[i] = x[t + 256 * i]; mx = fmaxf(mx, v[i]); }
#pragma unroll
  for (int o = 32; o > 0; o >>= 1) mx = fmaxf(mx, __shfl_xor(mx, o, 64));
  if ((t & 63) == 0) red[t >> 6] = mx;
  __syncthreads();
  mx = fmaxf(fmaxf(red[0], red[1]), fmaxf(red[2], red[3]));
  __syncthreads();
  float s = 0.f;
#pragma unroll
  for (int i = 0; i < 8; i++) { v[i] = __expf(v[i] - mx); s += v[i]; }
#pragma unroll
  for (int o = 32; o > 0; o >>= 1) s += __shfl_xor(s, o, 64);
  if ((t & 63) == 0) red[t >> 6] = s;
  __syncthreads();
  s = red[0] + red[1] + red[2] + red[3];
  float inv = 1.f / s;
#pragma unroll
  for (int i = 0; i < 8; i++) p[t + 256 * i] = (_Float16)(v[i] * inv);
}

// ---------------------------------------------------------------------------
extern "C" void kernel_launch(void* const* d_in, const int* in_sizes, int n_in,
                              void* d_out, int out_size, void* d_ws, size_t ws_size,
                              hipStream_t stream)
{
  const float* query = (const float*)d_in[0];
  const float* key_  = (const float*)d_in[1];
  const float* value = (const float*)d_in[2];
  const float* Wq = (const float*)d_in[3];
  const float* bq = (const float*)d_in[4];
  const float* Wk = (const float*)d_in[5];
  const float* bk = (const float*)d_in[6];
  const float* Wv = (const float*)d_in[7];
  const float* bv = (const float*)d_in[8];

  char* ws = (char*)d_ws;
  char* ob = (char*)d_out;
  const size_t M64 = (size_t)NB * MAT * 2;   // 64 MiB

  _Float16* q_h  = (_Float16*)(ws);                 // A[0,64)
  _Float16* k_h  = (_Float16*)(ws);                 // A[0,64) (q dead)
  _Float16* k_l  = (_Float16*)(ws + M64);           // A[64,128)
  float*    qk   = (float*)(ws);                    // A as f32 (k dead)
  _Float16* qT_h = (_Float16*)(ws + 2 * M64);       // D[128,192)
  _Float16* qT_l = (_Float16*)(ws + 3 * M64);       // D[192,256)
  _Float16* P    = qT_h;                            // after qT dead
  _Float16* vT   = qT_l;
  _Float16* kk_h = (_Float16*)(ws + 4 * M64);       // E[256,320)
  _Float16* val_h = (_Float16*)(ws + 5 * M64);      // E[320,384)

  _Float16* wq_h = (_Float16*)(ob);
  _Float16* wq_l = (_Float16*)(ob + (MAT * 2));
  _Float16* wk_h = (_Float16*)(ob + 2 * (MAT * 2));
  _Float16* wv_h = (_Float16*)(ob + 3 * (MAT * 2));
  float* out = (float*)d_out;

  dim3 blk256(256), blk512(512);
  dim3 gg(512);   // 8 batches x 8x8 tiles of 256
  const long NQ8 = (long)NB * MAT / 8;
  const long NW8 = MAT / 8;

  // 1. presplit query (hi only, x16), Wq (hi+lo, x16)
  presplit<false><<<dim3(2048), blk256, 0, stream>>>(query, q_h, nullptr, NQ8, 16.f);
  presplit<true><<<dim3(2048), blk256, 0, stream>>>(Wq, wq_h, wq_l, NW8, 16.f);
  // 2. qT[e][s] = sum_d Wq[e][d]*query[s][d] + bq[e] (row bias), split out
  gemm8<2, 2, 2><<<gg, blk512, 0, stream>>>(wq_h, wq_l, 0, q_h, MAT,
                                            bq, 1.f / 256.f, qT_h, qT_l, MAT);
  // 3. presplit key_ (hi+lo, x16), Wk (hi only, x16)
  presplit<true><<<dim3(2048), blk256, 0, stream>>>(key_, k_h, k_l, NQ8, 16.f);
  presplit<false><<<dim3(2048), blk256, 0, stream>>>(Wk, wk_h, nullptr, NW8, 16.f);
  // 4. kk[s'][e] = sum_d key_[s'][d]*Wk[e][d] + bk[e] (col bias), hi-only out
  gemm8<2, 1, 3><<<gg, blk512, 0, stream>>>(k_h, k_l, MAT, wk_h, 0,
                                            bk, 1.f / 256.f, kk_h, nullptr, MAT);
  // 5. qk[e][s'] = sum_m qT[e][m]*kk[s'][m]  (f32 out)
  gemm8<2, 0, 0><<<gg, blk512, 0, stream>>>(qT_h, qT_l, MAT, kk_h, MAT,
                                            nullptr, 1.f / 256.f, qk, nullptr, MAT);
  // 6. P = row-softmax(qk), fp16
  softmax_rows<<<dim3(NB * Sd), blk256, 0, stream>>>(qk, P);
  // 7. presplit value (x1), Wv (x1)
  presplit<false><<<dim3(2048), blk256, 0, stream>>>(value, val_h, nullptr, NQ8, 1.f);
  presplit<false><<<dim3(2048), blk256, 0, stream>>>(Wv, wv_h, nullptr, NW8, 1.f);
  // 8. vT[d'][s'] = sum_d Wv[d'][d]*value[s'][d] + bv[d'] (row bias), fp16
  gemm8<1, 2, 1><<<gg, blk512, 0, stream>>>(wv_h, nullptr, 0, val_h, MAT,
                                            bv, 1.f, vT, nullptr, MAT);
  // 9. out[d'][e] = sum_s' vT[d'][s']*P[e][s']  (f32 -> d_out)
  gemm8<1, 0, 0><<<gg, blk512, 0, stream>>>(vT, nullptr, MAT, P, MAT,
                                            nullptr, 1.f, out, nullptr, MAT);
}